// Round 12
// baseline (1021.301 us; speedup 1.0000x reference)
//
#include <hip/hip_runtime.h>

typedef __attribute__((ext_vector_type(8))) short bf16x8;
typedef __attribute__((ext_vector_type(4))) float f32x4;
typedef __attribute__((ext_vector_type(16))) float f32x16;
typedef __attribute__((ext_vector_type(4))) unsigned int u32x4;

constexpr int L_ = 4096, S_ = 4096, D_ = 2048, H_ = 16, HD_ = 128;
constexpr int LDSS = 72; // padded stride for the small kernels

__device__ __forceinline__ unsigned short f2bf(float f) {
    unsigned int u = __builtin_bit_cast(unsigned int, f);
    return (unsigned short)((u + 0x7fffu + ((u >> 16) & 1u)) >> 16);
}
__device__ __forceinline__ float bf2f(unsigned short h) {
    unsigned int u = ((unsigned int)h) << 16;
    return __builtin_bit_cast(float, u);
}
__device__ __forceinline__ unsigned long long pack4(float a, float b, float c, float d) {
    return (unsigned long long)f2bf(a) | ((unsigned long long)f2bf(b) << 16)
         | ((unsigned long long)f2bf(c) << 32) | ((unsigned long long)f2bf(d) << 48);
}
__device__ __forceinline__ float featmap(float x) {
    return x > 0.f ? x + 1.f : __expf(x);
}
__device__ __forceinline__ void gload16(const unsigned short* g, unsigned short* l) {
    __builtin_amdgcn_global_load_lds(
        (const __attribute__((address_space(1))) void*)g,
        (__attribute__((address_space(3))) void*)l, 16, 0, 0);
}

// fp32 -> bf16 bulk convert over up to 4 segments (one launch replaces 4)
__global__ __launch_bounds__(256) void cvt4(
    const float* __restrict__ s0, unsigned short* __restrict__ d0, int n0,
    const float* __restrict__ s1, unsigned short* __restrict__ d1, int n1,
    const float* __restrict__ s2, unsigned short* __restrict__ d2, int n2,
    const float* __restrict__ s3, unsigned short* __restrict__ d3, int n3)
{
    const int total = n0 + n1 + n2 + n3;
    const int stride = gridDim.x * 256;
    for (int i = blockIdx.x * 256 + threadIdx.x; i < total; i += stride) {
        const float* s; unsigned short* d; int j = i;
        if (j < n0) { s = s0; d = d0; }
        else if ((j -= n0) < n1) { s = s1; d = d1; }
        else if ((j -= n1) < n2) { s = s2; d = d2; }
        else { j -= n2; s = s3; d = d3; }
        const float4 a = ((const float4*)s)[2 * (size_t)j];
        const float4 b = ((const float4*)s)[2 * (size_t)j + 1];
        unsigned long long* o = (unsigned long long*)&d[(size_t)j * 8];
        o[0] = pack4(a.x, a.y, a.z, a.w);
        o[1] = pack4(b.x, b.y, b.z, b.w);
    }
}

// ====== 256x256 8-phase GEMM (R10 schedule) with 32x32x16 MFMA ======
// C = A @ B^T. BK=64, 2 K-tiles/iter (buf0/buf1). 8 waves (2wr x 4wc), per-wave C=128x64
// = 4 mf(32-row) x 2 nf(32-col) frags of 32x32, acc f32x16 each (128 regs, same as before).
// Per phase Q(MQ,NQ): 2 mf x 4 ks = 8 MFMA of 32x32x16 (same FLOPs as old 16, but the
// 32x32 pipe runs 2495 vs 2075 TF -> 17% less matrix-pipe time). ds_read counts unchanged.
// Fragment maps (m74/m101): C/D col=lane&31,row=(reg&3)+8*(reg>>2)+4*(lane>>5);
// A/B operand row=lane&31, k=(lane>>5)*8+e. Read swizzle: chunk=(ks*2+hi)^(lane&7),
// conflict-free (2-way within 16-lane quarter). Staging XOR keyed by row&7 — unchanged.
// Schedule/ledger identical to R10: B-prefetch into dead slots at P4/P8 after VM6;
// one barrier per phase; vmcnt(6) retires exactly one K-tile.
template<int MODE, int NBN>
__global__ __launch_bounds__(512, 2) void gemm256(
    const unsigned short* __restrict__ A, const unsigned short* __restrict__ B,
    unsigned short* __restrict__ C1, unsigned short* __restrict__ C2,
    float* __restrict__ Cf, const float* __restrict__ bias)
{
    __shared__ alignas(16) unsigned short lds[65536];   // 128 KiB
    const int tid = threadIdx.x;
    const int lane = tid & 63, w = tid >> 6;
    const int wr = w >> 2, wc = w & 3;
    const int l32 = lane & 31;                // fragment row/col
    const int hi = lane >> 5;                 // k-half selector
    const int rsw = (lane & 7) << 3;          // read-side swizzle (shorts), = (row&7)*8
    const int lsub = lane >> 3;               // 0..7 (staging row-in-octet)
    const int scol = ((lane & 7) ^ lsub) * 8; // pre-swizzled source col (elements)

    // XCD swizzle + 2x2 sub-block order within each XCD chunk (L2 locality).
    const int wg = blockIdx.x;
    const int xcd = wg & 7, u = wg >> 3;
    const int s = u >> 2, q = u & 3;
    const int sbm = s & 3, sbn = s >> 2;
    const int bm = xcd * 8 + sbm * 2 + (q & 1);
    const int bn = sbn * 2 + (q >> 1);
    const int row0 = bm * 256, bcol = bn * 256;

    const unsigned short* Ap = A + (size_t)row0 * D_;
    const unsigned short* Bp = B + (size_t)bcol * D_;
    const int rA = w * 8 + lsub;                              // A stage row (r=0)
    const int rB = ((w * 8 + lsub) >> 5) * 64 + ((w * 8 + lsub) & 31); // B stage row base

    f32x16 acc[4][2] = {};      // [global mf][nf]
    bf16x8 av[4][2], bv[4][2];  // [ks][mf-in-quadrant] / [ks][NQ-slot]

#define STA(BUF, HH, KT) do { \
    const unsigned short* g_ = Ap + (size_t)((HH) * 64 + rA) * D_ + (KT) * 64 + scol; \
    unsigned short* l_ = &lds[(BUF) * 16384 + (HH) * 8192 + w * 512]; \
    gload16(g_, l_); gload16(g_ + (size_t)128 * D_, l_ + 4096); } while (0)

#define STB(BUF, HH, KT) do { \
    const unsigned short* g_ = Bp + (size_t)(rB + (HH) * 32) * D_ + (KT) * 64 + scol; \
    unsigned short* l_ = &lds[32768 + (BUF) * 16384 + (HH) * 8192 + w * 512]; \
    gload16(g_, l_); gload16(g_ + (size_t)128 * D_, l_ + 4096); } while (0)

// 8 ds_read_b128: av[ks][mf'] <- A-quadrant MQ of BUF (rows wr*64 + mf'*32 + l32)
#define RD_A(MQ, BUF) \
    _Pragma("unroll") for (int mf = 0; mf < 2; mf++) \
    _Pragma("unroll") for (int ks = 0; ks < 4; ks++) \
        av[ks][mf] = *(const bf16x8*)&lds[(BUF) * 16384 + (MQ) * 8192 \
            + (wr * 64 + mf * 32 + l32) * 64 + ((ks * 16 + hi * 8) ^ rsw)];

// 4 ds_read_b128: bv[ks][NQ] <- B-half NQ of BUF (rows wc*32 + l32)
#define RD_B(NQ, BUF) \
    _Pragma("unroll") for (int ks = 0; ks < 4; ks++) \
        bv[ks][NQ] = *(const bf16x8*)&lds[32768 + (BUF) * 16384 + (NQ) * 8192 \
            + (wc * 32 + l32) * 64 + ((ks * 16 + hi * 8) ^ rsw)];

// 8 MFMA of 32x32x16: quadrant (MQ, NQ)
#define MFMA_Q(MQ, NQ) \
    __builtin_amdgcn_s_setprio(1); \
    _Pragma("unroll") for (int mf = 0; mf < 2; mf++) \
    _Pragma("unroll") for (int ks = 0; ks < 4; ks++) \
        acc[(MQ) * 2 + mf][NQ] = __builtin_amdgcn_mfma_f32_32x32x16_bf16( \
            av[ks][mf], bv[ks][NQ], acc[(MQ) * 2 + mf][NQ], 0, 0, 0); \
    __builtin_amdgcn_s_setprio(0);

#define SB0 __builtin_amdgcn_sched_barrier(0)
#define BAR __builtin_amdgcn_s_barrier()
#define VM6 asm volatile("s_waitcnt vmcnt(6)" ::: "memory")
#define VM0 asm volatile("s_waitcnt vmcnt(0)" ::: "memory")

    // ---- prologue: tile0 (8 loads) + tile1 partial {A0,B0,B1} (6 loads) ----
    STA(0, 0, 0); STB(0, 0, 0); STB(0, 1, 0); STA(0, 1, 0);
    STA(1, 0, 1); STB(1, 0, 1); STB(1, 1, 1);
    VM6;            // retires tile0's 8 loads
    BAR;
    RD_B(0, 0); RD_B(1, 0);     // bv0,bv1 <- B halves (tile0)

    constexpr int NT = D_ / 64;       // 32 K-tiles
    for (int i = 0; i < NT / 2 - 1; i++) {
        const int T = 2 * i;
        // P1: Q(0,0) on [av<-A0(buf0), bv0]; stage a
        RD_A(0, 0); STA(1, 1, T + 1);
        MFMA_Q(0, 0); SB0; BAR;
        // P2: Q(0,1) on [av, bv1] (no reads); stage b
        STA(0, 0, T + 2);
        MFMA_Q(0, 1); SB0; BAR;
        // P3: Q(1,1) on [av<-A1(buf0), bv1]; stage c
        RD_A(1, 0); STB(0, 0, T + 2);
        MFMA_Q(1, 1); SB0; BAR;
        // P4: Q(1,0) on [av, bv0]; stage d; gate tile T+1; prefetch B(buf1)
        STB(0, 1, T + 2);
        MFMA_Q(1, 0);
        VM6; RD_B(0, 1); RD_B(1, 1);
        SB0; BAR;
        // P5: Q(0,0)(buf1); stage e
        RD_A(0, 1); STA(0, 1, T + 2);
        MFMA_Q(0, 0); SB0; BAR;
        // P6: Q(0,1) (no reads); stage f
        STA(1, 0, T + 3);
        MFMA_Q(0, 1); SB0; BAR;
        // P7: Q(1,1) on [av<-A1(buf1), bv1]; stage g
        RD_A(1, 1); STB(1, 0, T + 3);
        MFMA_Q(1, 1); SB0; BAR;
        // P8: Q(1,0); stage h; gate tile T+2; prefetch B(buf0)
        STB(1, 1, T + 3);
        MFMA_Q(1, 0);
        VM6; RD_B(0, 0); RD_B(1, 0);
        SB0; BAR;
    }
    // ---- peeled final body (tiles NT-2 buf0, NT-1 buf1): only stage a remains ----
    {
        RD_A(0, 0); STA(1, 1, NT - 1);
        MFMA_Q(0, 0); SB0; BAR;
        MFMA_Q(0, 1); SB0; BAR;
        RD_A(1, 0);
        MFMA_Q(1, 1); SB0; BAR;
        MFMA_Q(1, 0);
        VM0; RD_B(0, 1); RD_B(1, 1);    // drain f,g,h,a then read B(buf1)
        SB0; BAR;
        RD_A(0, 1);
        MFMA_Q(0, 0); SB0; BAR;
        MFMA_Q(0, 1); SB0; BAR;
        RD_A(1, 1);
        MFMA_Q(1, 1); SB0; BAR;
        MFMA_Q(1, 0); SB0; BAR;
    }

    // ================= epilogue =================
    // C/D map: col = l32, row = (reg&3) + 8*(reg>>2) + 4*hi
    const bool second = bn >= (NBN / 2);
    if (MODE == 1) {
        // transpose each 128(s) x 128(d) quadrant via LDS, store [bh][d][s]
        unsigned short* TT = lds;             // 128*136 shorts
        const int b = row0 >> 12;
        #pragma unroll
        for (int qd = 0; qd < 4; qd++) {
            const int sq = qd >> 1, dh = qd & 1;
            __syncthreads();
            if (wr == sq && (wc >> 1) == dh) {
                #pragma unroll
                for (int m = 0; m < 4; m++) {
                    #pragma unroll
                    for (int nf = 0; nf < 2; nf++) {
                        #pragma unroll
                        for (int g = 0; g < 4; g++) {
                            float x0 = acc[m][nf][4 * g + 0], x1 = acc[m][nf][4 * g + 1];
                            float x2 = acc[m][nf][4 * g + 2], x3 = acc[m][nf][4 * g + 3];
                            if (!second) {
                                x0 = featmap(x0); x1 = featmap(x1);
                                x2 = featmap(x2); x3 = featmap(x3);
                            }
                            const int dcol = (wc & 1) * 64 + nf * 32 + l32;
                            const int srow = m * 32 + g * 8 + hi * 4;
                            *(unsigned long long*)&TT[dcol * 136 + srow]
                                = pack4(x0, x1, x2, x3);
                        }
                    }
                }
            }
            __syncthreads();
            const int h2 = (bn & 7) * 2 + dh;
            const int s0 = (row0 + sq * 128) & (S_ - 1);
            unsigned short* dst = (second ? C2 : C1) + (size_t)(b * H_ + h2) * HD_ * S_;
            #pragma unroll
            for (int it = 0; it < 4; it++) {
                const int idx = it * 512 + tid;
                const int d = idx >> 4, sc2 = (idx & 15) * 8;
                *(u32x4*)&dst[(size_t)d * S_ + s0 + sc2] = *(const u32x4*)&TT[d * 136 + sc2];
            }
        }
        return;
    }
    #pragma unroll
    for (int m = 0; m < 4; m++) {
        #pragma unroll
        for (int nf = 0; nf < 2; nf++) {
            #pragma unroll
            for (int reg = 0; reg < 16; reg++) {
                const int crow = (reg & 3) + 8 * (reg >> 2) + 4 * hi;
                const size_t gr = (size_t)(row0 + wr * 128 + m * 32 + crow);
                const int gc = bcol + wc * 64 + nf * 32 + l32;
                float x = acc[m][nf][reg];
                if (MODE == 0) {
                    if (!second) {
                        C1[gr * D_ + gc] = f2bf(featmap(x));
                    } else {
                        const int gc2 = gc - D_;
                        float t = x + bias[gc2];
                        C2[gr * D_ + gc2] = f2bf(1.f / (1.f + __expf(-t)));
                    }
                } else {
                    Cf[gr * D_ + gc] = x;
                }
            }
        }
    }
#undef STA
#undef STB
#undef RD_A
#undef RD_B
#undef MFMA_Q
#undef SB0
#undef BAR
#undef VM6
#undef VM0
}

// kv_summary partials: per (s-chunk cx, bh): part[cx][bh][d][e] = sum_s k[s,d]*v[s,e]
__global__ __launch_bounds__(256) void kvsum_part(
    const unsigned short* __restrict__ kT, const unsigned short* __restrict__ vT,
    float* __restrict__ part, float* __restrict__ ksum_part)
{
    __shared__ unsigned short kA[HD_ * LDSS];
    __shared__ unsigned short vB[HD_ * LDSS];
    __shared__ float red[HD_ * 8];
    const int tid = threadIdx.x;
    const int cx = blockIdx.x, bh = blockIdx.y;
    const int lane = tid & 63, w = tid >> 6;
    const int wm = (w >> 1) * 64, wn = (w & 1) * 64;
    const int lr = lane & 15, lk = (lane >> 4) * 8;
    const unsigned short* kb = kT + (size_t)bh * HD_ * S_;
    const unsigned short* vb = vT + (size_t)bh * HD_ * S_;
    f32x4 acc[4][4] = {};
    float ksl[4] = {0.f, 0.f, 0.f, 0.f};
    const int chunk = S_ / 8;
    const int s_begin = cx * chunk;
    for (int s0 = s_begin; s0 < s_begin + chunk; s0 += 64) {
        #pragma unroll
        for (int i = 0; i < 4; i++) {
            int idx = tid + i * 256;
            int d = idx >> 3, sc = (idx & 7) * 8;
            u32x4 kk = *(const u32x4*)&kb[(size_t)d * S_ + s0 + sc];
            *(u32x4*)&kA[d * LDSS + sc] = kk;
            unsigned short t8[8];
            *(u32x4*)t8 = kk;
            float ss = 0.f;
            #pragma unroll
            for (int j = 0; j < 8; j++) ss += bf2f(t8[j]);
            ksl[i] += ss;
            *(u32x4*)&vB[d * LDSS + sc] = *(const u32x4*)&vb[(size_t)d * S_ + s0 + sc];
        }
        __syncthreads();
        #pragma unroll
        for (int ks = 0; ks < 64; ks += 32) {
            bf16x8 av[4], bv[4];
            #pragma unroll
            for (int mi = 0; mi < 4; mi++)
                av[mi] = *(const bf16x8*)&kA[(wm + mi * 16 + lr) * LDSS + ks + lk];
            #pragma unroll
            for (int ni = 0; ni < 4; ni++)
                bv[ni] = *(const bf16x8*)&vB[(wn + ni * 16 + lr) * LDSS + ks + lk];
            #pragma unroll
            for (int mi = 0; mi < 4; mi++)
                #pragma unroll
                for (int ni = 0; ni < 4; ni++)
                    acc[mi][ni] = __builtin_amdgcn_mfma_f32_16x16x32_bf16(
                        av[mi], bv[ni], acc[mi][ni], 0, 0, 0);
        }
        __syncthreads();
    }
    #pragma unroll
    for (int i = 0; i < 4; i++) red[((tid >> 3) + 32 * i) * 8 + (tid & 7)] = ksl[i];
    __syncthreads();
    if (tid < HD_) {
        float s = 0.f;
        #pragma unroll
        for (int j = 0; j < 8; j++) s += red[tid * 8 + j];
        ksum_part[(size_t)cx * (64 * HD_) + bh * HD_ + tid] = s;
    }
    const int rb = (lane >> 4) * 4;
    float* pp = part + ((size_t)cx * 64 + bh) * (HD_ * HD_);
    #pragma unroll
    for (int mi = 0; mi < 4; mi++)
        #pragma unroll
        for (int ni = 0; ni < 4; ni++)
            #pragma unroll
            for (int r = 0; r < 4; r++)
                pp[(wm + mi * 16 + rb + r) * HD_ + wn + ni * 16 + lr] = acc[mi][ni][r];
}

__global__ __launch_bounds__(256) void kvs_reduce(
    const float* __restrict__ part, unsigned short* __restrict__ kvsT,
    const float* __restrict__ ksum_part, float* __restrict__ ksum)
{
    const int idx = blockIdx.x * 256 + threadIdx.x;
    const int e = idx & 127, d2 = (idx >> 7) & 127, bh = idx >> 14;
    float s = 0.f;
    #pragma unroll
    for (int cx = 0; cx < 8; cx++)
        s += part[((size_t)cx * 64 + bh) * 16384 + d2 * 128 + e];
    kvsT[((size_t)bh * 128 + e) * 128 + d2] = f2bf(s);
    if (idx < 64 * 128) {
        float t = 0.f;
        #pragma unroll
        for (int cx = 0; cx < 8; cx++) t += ksum_part[cx * 8192 + idx];
        ksum[idx] = t;
    }
}

// attn = (q @ kvs) * z * gate -> y (bf16)
__global__ __launch_bounds__(256) void attn_kernel(
    const unsigned short* __restrict__ qf, const unsigned short* __restrict__ kvsT,
    const float* __restrict__ ksum, const unsigned short* __restrict__ gate,
    unsigned short* __restrict__ y)
{
    __shared__ unsigned short qs[128 * 136];
    __shared__ unsigned short bs[128 * LDSS];
    __shared__ float zl[128];
    const int tid = threadIdx.x;
    const int l0 = blockIdx.x * 128;
    const int h = blockIdx.y, b = blockIdx.z;
    const int bh = b * H_ + h;
    const int lane = tid & 63, w = tid >> 6;
    const int wm = (w >> 1) * 64, wn = (w & 1) * 64;
    const int lr = lane & 15, lk = (lane >> 4) * 8;
    const size_t qbase = (size_t)b * L_ * D_ + (size_t)h * HD_;
    #pragma unroll
    for (int i = 0; i < 8; i++) {
        int idx = tid + i * 256;
        int r = idx >> 4, c = (idx & 15) * 8;
        *(u32x4*)&qs[r * 136 + c] = *(const u32x4*)&qf[qbase + (size_t)(l0 + r) * D_ + c];
    }
    __syncthreads();
    if (tid < 128) {
        const float* kp = ksum + bh * HD_;
        float sden = 0.f;
        #pragma unroll 4
        for (int d2 = 0; d2 < HD_; d2++) sden += bf2f(qs[tid * 136 + d2]) * kp[d2];
        zl[tid] = 1.f / (sden + 1e-6f);
    }
    f32x4 acc[4][4] = {};
    for (int kc = 0; kc < 2; kc++) {
        #pragma unroll
        for (int i = 0; i < 4; i++) {
            int idx = tid + i * 256;
            int e = idx >> 3, dc = (idx & 7) * 8;
            *(u32x4*)&bs[e * LDSS + dc] =
                *(const u32x4*)&kvsT[((size_t)bh * 128 + e) * 128 + kc * 64 + dc];
        }
        __syncthreads();
        #pragma unroll
        for (int ks = 0; ks < 64; ks += 32) {
            bf16x8 av[4], bv[4];
            #pragma unroll
            for (int mi = 0; mi < 4; mi++)
                av[mi] = *(const bf16x8*)&qs[(wm + mi * 16 + lr) * 136 + kc * 64 + ks + lk];
            #pragma unroll
            for (int ni = 0; ni < 4; ni++)
                bv[ni] = *(const bf16x8*)&bs[(wn + ni * 16 + lr) * LDSS + ks + lk];
            #pragma unroll
            for (int mi = 0; mi < 4; mi++)
                #pragma unroll
                for (int ni = 0; ni < 4; ni++)
                    acc[mi][ni] = __builtin_amdgcn_mfma_f32_16x16x32_bf16(
                        av[mi], bv[ni], acc[mi][ni], 0, 0, 0);
        }
        __syncthreads();
    }
    const int rb = (lane >> 4) * 4;
    #pragma unroll
    for (int mi = 0; mi < 4; mi++) {
        #pragma unroll
        for (int ni = 0; ni < 4; ni++) {
            #pragma unroll
            for (int r = 0; r < 4; r++) {
                int ll = wm + mi * 16 + rb + r;
                int e = wn + ni * 16 + lr;
                float attn = acc[mi][ni][r] * zl[ll];
                float g = bf2f(gate[qbase + (size_t)(l0 + ll) * D_ + e]);
                y[qbase + (size_t)(l0 + ll) * D_ + e] = f2bf(attn * g);
            }
        }
    }
}

extern "C" void kernel_launch(void* const* d_in, const int* in_sizes, int n_in,
                              void* d_out, int out_size, void* d_ws, size_t ws_size,
                              hipStream_t stream)
{
    (void)in_sizes; (void)n_in; (void)out_size; (void)ws_size;
    const float* query = (const float*)d_in[0];
    const float* kv    = (const float*)d_in[1];
    const float* Wq    = (const float*)d_in[2];
    const float* Wg    = (const float*)d_in[3];
    const float* bg    = (const float*)d_in[4];
    const float* Wkv   = (const float*)d_in[5];
    const float* Wo    = (const float*)d_in[6];
    float* out = (float*)d_out;
    char* ws = (char*)d_ws;

    // workspace layout (bytes). Region R is time-shared (stream-ordered).
    unsigned short* q_feat = (unsigned short*)(ws);                 // 64 MiB
    unsigned short* gate   = (unsigned short*)(ws + 67108864);      // 64 MiB
    unsigned short* kTb    = (unsigned short*)(ws + 134217728);     // 64 MiB [bh][d][s]
    unsigned short* vTb    = (unsigned short*)(ws + 201326592);     // 64 MiB [bh][d][s]
    char* R = ws + 268435456;
    unsigned short* qbf    = (unsigned short*)(R);                  // 64 MiB (phase1)
    unsigned short* Wqg    = (unsigned short*)(R + 67108864);       // 16 MiB (phase1)
    unsigned short* kvbf   = (unsigned short*)(R);                  // 64 MiB (phase2)
    unsigned short* Wkvb   = (unsigned short*)(R + 67108864);       // 16 MiB (phase2)
    float* part            = (float*)(R);                           // 32 MiB (phase3)
    float* ksum_part       = (float*)(R + 33554432);                // 256 KiB
    float* ksum            = (float*)(R + 33816576);                // 32 KiB
    unsigned short* kvsT   = (unsigned short*)(R + 33849344);       // 2 MiB
    unsigned short* Wob    = (unsigned short*)(R + 83886080);       // 8 MiB
    unsigned short* ybuf   = kTb;   // kT dead after kvsum_part

    dim3 blk(256, 1, 1);
    dim3 blk512(512, 1, 1);
    // ---- phase 1: q path (single cvt launch for query+Wq+Wg+Wo) ----
    cvt4<<<dim3(2048), blk, 0, stream>>>(query, qbf, 4194304,
                                         Wq, Wqg, 524288,
                                         Wg, Wqg + 4194304, 524288,
                                         Wo, Wob, 524288);
    gemm256<0, 16><<<dim3(1024), blk512, 0, stream>>>(qbf, Wqg, q_feat, gate, nullptr, bg);
    // ---- phase 2: kv path ----
    cvt4<<<dim3(2048), blk, 0, stream>>>(kv, kvbf, 4194304,
                                         Wkv, Wkvb, 1048576,
                                         nullptr, nullptr, 0,
                                         nullptr, nullptr, 0);
    gemm256<1, 16><<<dim3(1024), blk512, 0, stream>>>(kvbf, Wkvb, kTb, vTb, nullptr, nullptr);
    // ---- phase 3: summary + attention ----
    kvsum_part<<<dim3(8, 64), blk, 0, stream>>>(kTb, vTb, part, ksum_part);
    kvs_reduce<<<dim3(4096), blk, 0, stream>>>(part, kvsT, ksum_part, ksum);
    attn_kernel<<<dim3(32, 16, 4), blk, 0, stream>>>(q_feat, kvsT, ksum, gate, ybuf);
    // ---- output projection ----
    gemm256<2, 8><<<dim3(512), blk512, 0, stream>>>(ybuf, Wob, nullptr, nullptr, out, nullptr);
}